// Round 13
// baseline (684.465 us; speedup 1.0000x reference)
//
#include <hip/hip_runtime.h>

#define N_NODES 50000
#define N_EDGES 800000
#define BGRAPH  256
#define DIM     128
#define NLAYER  4
#define EPS     1e-5f
#define NBUCK   ((N_NODES + 255) / 256)   // 196 buckets of 256 nodes
#define WSZ     (384 * DIM)               // 49152 weights per layer
#define EB_PER  4096                      // edges per bexpand block
#define PROP_BLOCKS ((N_NODES + 63) / 64) // 782 blocks per column-pass (64 nodes/block)

typedef _Float16 half8_t __attribute__((ext_vector_type(8)));
typedef float    f32x4   __attribute__((ext_vector_type(4)));

// ---------------- CSR build v2: bucketed, write-locality-friendly ----------------
__global__ __launch_bounds__(1024) void bcount_kernel(const int* __restrict__ dst,
                                                      int* __restrict__ bcnt) {
    __shared__ int h[NBUCK];
    int t = threadIdx.x;
    if (t < NBUCK) h[t] = 0;
    __syncthreads();
    for (int e = blockIdx.x * 1024 + t; e < N_EDGES; e += gridDim.x * 1024)
        atomicAdd(&h[dst[e] >> 8], 1);
    __syncthreads();
    if (t < NBUCK && h[t]) atomicAdd(&bcnt[t], h[t]);
}

__global__ void bscan_kernel(const int* __restrict__ bcnt, int* __restrict__ boff,
                             int* __restrict__ bcur) {
    __shared__ int lds[256];
    int t = threadIdx.x;
    int v = (t < NBUCK) ? bcnt[t] : 0;
    lds[t] = v;
    __syncthreads();
    for (int off = 1; off < 256; off <<= 1) {
        int u = (t >= off) ? lds[t - off] : 0;
        __syncthreads();
        lds[t] += u;
        __syncthreads();
    }
    if (t < NBUCK) { int ex = lds[t] - v; boff[t] = ex; bcur[t] = ex; }
    if (t == NBUCK - 1) boff[NBUCK] = lds[t];
}

__global__ __launch_bounds__(1024) void bexpand_kernel(const int* __restrict__ src,
                                                       const int* __restrict__ dst,
                                                       int* __restrict__ bcur,
                                                       int2* __restrict__ ebuf) {
    __shared__ int2 stage[EB_PER];       // 32 KB
    __shared__ int hist[NBUCK];
    __shared__ int lofs[NBUCK];
    __shared__ int lcur[NBUCK];
    __shared__ int gbase[NBUCK];
    __shared__ int s[256];
    int t = threadIdx.x;
    int e0 = blockIdx.x * EB_PER;
    int total = N_EDGES - e0; if (total > EB_PER) total = EB_PER;
    if (t < NBUCK) hist[t] = 0;
    __syncthreads();
    int mys[4], myd[4], myb[4];
#pragma unroll
    for (int j = 0; j < 4; ++j) {
        int e = e0 + t + j * 1024;
        if (e < N_EDGES) {
            mys[j] = src[e]; myd[j] = dst[e]; myb[j] = myd[j] >> 8;
            atomicAdd(&hist[myb[j]], 1);
        } else myb[j] = -1;
    }
    __syncthreads();
    if (t < 256) s[t] = (t < NBUCK) ? hist[t] : 0;
    __syncthreads();
    for (int off = 1; off < 256; off <<= 1) {
        int u = 0;
        if (t < 256 && t >= off) u = s[t - off];
        __syncthreads();
        if (t < 256) s[t] += u;
        __syncthreads();
    }
    if (t < NBUCK) {
        int v = hist[t];
        int ex = s[t] - v;
        lofs[t] = ex; lcur[t] = ex;
        gbase[t] = (v > 0) ? atomicAdd(&bcur[t], v) : 0;
    }
    __syncthreads();
#pragma unroll
    for (int j = 0; j < 4; ++j) if (myb[j] >= 0) {
        int p = atomicAdd(&lcur[myb[j]], 1);
        stage[p] = make_int2(mys[j], myd[j]);
    }
    __syncthreads();
    for (int i = t; i < total; i += 1024) {
        int2 p = stage[i];
        int bu = p.y >> 8;
        ebuf[gbase[bu] + (i - lofs[bu])] = p;
    }
}

__global__ __launch_bounds__(256) void bbuild_kernel(const int2* __restrict__ ebuf,
                                                     const int* __restrict__ boff,
                                                     int* __restrict__ row_ptr,
                                                     float* __restrict__ dsq,
                                                     float* __restrict__ invd,
                                                     int* __restrict__ csr_src) {
    __shared__ int hist[256];
    __shared__ int s[256];
    __shared__ int lcur[256];
    int b = blockIdx.x, t = threadIdx.x;
    int base = boff[b], cnt = boff[b + 1] - base;
    int node0 = b << 8;
    hist[t] = 0;
    __syncthreads();
    for (int i = t; i < cnt; i += 256)
        atomicAdd(&hist[ebuf[base + i].y & 255], 1);
    __syncthreads();
    int v = hist[t];
    s[t] = v;
    __syncthreads();
    for (int off = 1; off < 256; off <<= 1) {
        int u = (t >= off) ? s[t - off] : 0;
        __syncthreads();
        s[t] += u;
        __syncthreads();
    }
    int excl = s[t] - v;
    lcur[t] = excl;
    int n = node0 + t;
    if (n < N_NODES) {
        row_ptr[n] = base + excl;
        float d = (float)(v < 1 ? 1 : v);
        dsq[n] = 1.0f / sqrtf(d);
        invd[n] = sqrtf(d);
        if (n == N_NODES - 1) row_ptr[N_NODES] = base + excl + v;   // = E
    }
    __syncthreads();
    for (int i = t; i < cnt; i += 256) {
        int2 p = ebuf[base + i];
        int slot = atomicAdd(&lcur[p.y & 255], 1);
        csr_src[base + slot] = p.x;
    }
}

// ---------------- W pack to MFMA B-fragment order ----------------
__global__ void wcvt_kernel(const float* __restrict__ W, _Float16* __restrict__ Wp) {
    int idx = blockIdx.x * blockDim.x + threadIdx.x;
    if (idx >= NLAYER * WSZ) return;
    int l = idx / WSZ;
    int r = idx - l * WSZ;
    int j = r & 7, lane = (r >> 3) & 63, t = (r >> 9) & 7, kb = r >> 12;
    int k = (kb << 5) + ((lane >> 4) << 3) + j;
    int n = (t << 4) + (lane & 15);
    Wp[idx] = (_Float16)W[l * WSZ + (k << 7) + n];
}

// ---------------- atom encoder: H16s = f16(dsq*H) only ----------------
__global__ void encode_kernel(const int* __restrict__ h_idx,
                              const float* __restrict__ atom_emb,
                              const float* __restrict__ dsq,
                              _Float16* __restrict__ H16s) {
    int n = blockIdx.x;
    int d = threadIdx.x;
    float acc = 0.0f;
#pragma unroll
    for (int f = 0; f < 9; ++f) {
        int idx = h_idx[n * 9 + f];
        acc += atom_emb[(f * 100 + idx) * DIM + d];
    }
    H16s[n * DIM + d] = (_Float16)(acc * dsq[n]);
}

// ---------------- pull prop v5: 4 column passes (32 cols = 64 B/row/pass, L2-resident) ----------------
// 4 lanes/node, 64 nodes/block. pass = blockIdx.x / PROP_BLOCKS (dispatch-order locality).
#define ACC8(r) { _Pragma("unroll") for (int jj = 0; jj < 8; ++jj) acc[jj] += (float)(r)[jj]; }
__global__ void prop_kernel(const int* __restrict__ row_ptr, const int* __restrict__ csr_src,
                            const float* __restrict__ dsq, const float* __restrict__ invd,
                            const _Float16* __restrict__ Gin, const _Float16* __restrict__ X0s,
                            float alpha, float beta, _Float16* __restrict__ Gout) {
    int pass = blockIdx.x / PROP_BLOCKS;
    int blk  = blockIdx.x - pass * PROP_BLOCKS;
    int n = blk * 64 + (threadIdx.x >> 2);
    if (n >= N_NODES) return;
    int q = (pass << 5) + ((threadIdx.x & 3) << 3);    // f16 column offset
    const _Float16* gq = Gin + q;
    int i = row_ptr[n], endp = row_ptr[n + 1];
    float acc[8];
#pragma unroll
    for (int j = 0; j < 8; ++j) acc[j] = 0.f;

    if (i + 8 <= endp) {
        int s0 = csr_src[i], s1 = csr_src[i+1], s2 = csr_src[i+2], s3 = csr_src[i+3];
        half8_t a0 = *(const half8_t*)&gq[(size_t)s0 * DIM];
        half8_t a1 = *(const half8_t*)&gq[(size_t)s1 * DIM];
        half8_t a2 = *(const half8_t*)&gq[(size_t)s2 * DIM];
        half8_t a3 = *(const half8_t*)&gq[(size_t)s3 * DIM];
        i += 4;
        for (; i + 4 <= endp; i += 4) {
            int t0 = csr_src[i], t1 = csr_src[i+1], t2 = csr_src[i+2], t3 = csr_src[i+3];
            half8_t b0 = *(const half8_t*)&gq[(size_t)t0 * DIM];
            half8_t b1 = *(const half8_t*)&gq[(size_t)t1 * DIM];
            half8_t b2 = *(const half8_t*)&gq[(size_t)t2 * DIM];
            half8_t b3 = *(const half8_t*)&gq[(size_t)t3 * DIM];
            ACC8(a0); ACC8(a1); ACC8(a2); ACC8(a3);
            a0 = b0; a1 = b1; a2 = b2; a3 = b3;
        }
        ACC8(a0); ACC8(a1); ACC8(a2); ACC8(a3);
    } else if (i + 4 <= endp) {
        int s0 = csr_src[i], s1 = csr_src[i+1], s2 = csr_src[i+2], s3 = csr_src[i+3];
        half8_t r0 = *(const half8_t*)&gq[(size_t)s0 * DIM];
        half8_t r1 = *(const half8_t*)&gq[(size_t)s1 * DIM];
        half8_t r2 = *(const half8_t*)&gq[(size_t)s2 * DIM];
        half8_t r3 = *(const half8_t*)&gq[(size_t)s3 * DIM];
        ACC8(r0); ACC8(r1); ACC8(r2); ACC8(r3);
        i += 4;
    }
    for (; i < endp; ++i) {
        int s = csr_src[i];
        half8_t r = *(const half8_t*)&gq[(size_t)s * DIM];
        ACC8(r);
    }

    float g = dsq[n];
    float a = alpha * g;
    half8_t out;
    if (beta != 0.0f) {
        float bi = beta * invd[n];
        half8_t x0 = *(const half8_t*)&X0s[(size_t)n * DIM + q];
#pragma unroll
        for (int j = 0; j < 8; ++j)
            out[j] = (_Float16)((a * acc[j] + bi * (float)x0[j]) * g);
    } else {
#pragma unroll
        for (int j = 0; j < 8; ++j)
            out[j] = (_Float16)(a * acc[j] * g);
    }
    *(half8_t*)&Gout[(size_t)n * DIM + q] = out;
}

// ---------------- MFMA GEMM v4: software-pipelined A+W loads ----------------
__global__ __launch_bounds__(256) void gemm_kernel(
        const _Float16* __restrict__ X0s, const _Float16* __restrict__ X1s,
        const _Float16* __restrict__ X2s, const float* __restrict__ invd,
        const _Float16* __restrict__ Wp,
        _Float16* __restrict__ Out16, float* __restrict__ stats) {
    const int tid  = threadIdx.x;
    const int wave = tid >> 6;
    const int lane = tid & 63;
    const int quad = lane >> 4;
    const int l15  = lane & 15;
    const int row0 = blockIdx.x * 128 + wave * 32;
    const int rA = row0 + l15;
    const int rB = row0 + 16 + l15;
    const int rAc = (rA < N_NODES) ? rA : (N_NODES - 1);
    const int rBc = (rB < N_NODES) ? rB : (N_NODES - 1);
    const _Float16 h0 = (_Float16)((rA < N_NODES) ? invd[rA] : 0.0f);
    const _Float16 h1 = (_Float16)((rB < N_NODES) ? invd[rB] : 0.0f);

    f32x4 acc0[8], acc1[8];
#pragma unroll
    for (int t = 0; t < 8; ++t) {
        acc0[t] = (f32x4){0.f, 0.f, 0.f, 0.f};
        acc1[t] = (f32x4){0.f, 0.f, 0.f, 0.f};
    }

    const _Float16* bufs[3] = {X0s, X1s, X2s};

    half8_t a0c, a1c, a0n, a1n, bc[8], bn[8];
    {
        const _Float16* Xb = bufs[0];
        const int c0 = (quad << 3);
        a0c = *(const half8_t*)&Xb[(size_t)rAc * DIM + c0];
        a1c = *(const half8_t*)&Xb[(size_t)rBc * DIM + c0];
        const _Float16* wl = Wp + (size_t)lane * 8;
#pragma unroll
        for (int t = 0; t < 8; ++t) bc[t] = *(const half8_t*)&wl[t << 9];
    }

    for (int kb = 0; kb < 12; ++kb) {
        if (kb < 11) {
            const int kn = kb + 1;
            const _Float16* Xb = bufs[kn >> 2];
            const int c0 = ((kn & 3) << 5) + (quad << 3);
            a0n = *(const half8_t*)&Xb[(size_t)rAc * DIM + c0];
            a1n = *(const half8_t*)&Xb[(size_t)rBc * DIM + c0];
            const _Float16* wl = Wp + (size_t)((kn << 9) + lane) * 8;
#pragma unroll
            for (int t = 0; t < 8; ++t) bn[t] = *(const half8_t*)&wl[t << 9];
        }
        half8_t a0, a1;
#pragma unroll
        for (int j = 0; j < 8; ++j) { a0[j] = a0c[j] * h0; a1[j] = a1c[j] * h1; }
#pragma unroll
        for (int t = 0; t < 8; ++t) {
            acc0[t] = __builtin_amdgcn_mfma_f32_16x16x32_f16(a0, bc[t], acc0[t], 0, 0, 0);
            acc1[t] = __builtin_amdgcn_mfma_f32_16x16x32_f16(a1, bc[t], acc1[t], 0, 0, 0);
        }
        if (kb < 11) {
            a0c = a0n; a1c = a1n;
#pragma unroll
            for (int t = 0; t < 8; ++t) bc[t] = bn[t];
        }
    }

    __shared__ float sred[4][DIM];
    __shared__ float s2red[4][DIM];
#pragma unroll
    for (int t = 0; t < 8; ++t) {
        const int c = (t << 4) + l15;
        float s = 0.f, s2 = 0.f;
#pragma unroll
        for (int reg = 0; reg < 4; ++reg) {
            float v0 = acc0[t][reg];
            float v1 = acc1[t][reg];
            s += v0 + v1; s2 += v0 * v0 + v1 * v1;
            int r0r = row0 + (quad << 2) + reg;
            int r1r = r0r + 16;
            if (r0r < N_NODES) Out16[(size_t)r0r * DIM + c] = (_Float16)v0;
            if (r1r < N_NODES) Out16[(size_t)r1r * DIM + c] = (_Float16)v1;
        }
        s  += __shfl_xor(s, 16);  s  += __shfl_xor(s, 32);
        s2 += __shfl_xor(s2, 16); s2 += __shfl_xor(s2, 32);
        if (quad == 0) { sred[wave][c] = s; s2red[wave][c] = s2; }
    }
    __syncthreads();
    if (tid < DIM) {
        float s = 0.f, s2 = 0.f;
#pragma unroll
        for (int w = 0; w < 4; ++w) { s += sred[w][tid]; s2 += s2red[w][tid]; }
        atomicAdd(&stats[tid], s);
        atomicAdd(&stats[DIM + tid], s2);
    }
}

// ---------------- BN apply + relu + residual (H16s-only residual stream) ----------------
__global__ void bnapply_kernel(const _Float16* __restrict__ Out16, const float* __restrict__ stats,
                               const float* __restrict__ gamma, const float* __restrict__ beta,
                               const float* __restrict__ dsq, const float* __restrict__ invd,
                               _Float16* __restrict__ H16s) {
    int idx = blockIdx.x * blockDim.x + threadIdx.x;
    if (idx >= N_NODES * DIM) return;
    int d = idx & 127;
    int n = idx >> 7;
    const float invN = 1.0f / (float)N_NODES;
    float mu  = stats[d] * invN;
    float var = stats[DIM + d] * invN - mu * mu;
    float sc  = (1.0f / sqrtf(var + EPS)) * gamma[d];
    float sh  = beta[d] - mu * sc;
    float v = (float)Out16[idx] * sc + sh;
    float h = (float)H16s[idx] * invd[n] + fmaxf(v, 0.0f);
    H16s[idx] = (_Float16)(h * dsq[n]);
}

// ---------------- mean pool (reconstruct H = H16s*invd) ----------------
#define PCHUNK 64
__global__ void pool_kernel(const _Float16* __restrict__ H16s, const float* __restrict__ invd,
                            const int* __restrict__ n2g,
                            float* __restrict__ sums, float* __restrict__ cnts) {
    int d = threadIdx.x;
    int r0 = blockIdx.x * PCHUNK;
    int rend = r0 + PCHUNK; if (rend > N_NODES) rend = N_NODES;
    if (r0 >= N_NODES) return;
    float acc = 0.0f;
    int cur = n2g[r0];
    int runlen = 0;
    for (int r = r0; r < rend; ++r) {
        int g = n2g[r];
        if (g != cur) {
            atomicAdd(&sums[cur * DIM + d], acc);
            if (d == 0) atomicAdd(&cnts[cur], (float)runlen);
            acc = 0.0f; runlen = 0; cur = g;
        }
        acc += (float)H16s[(size_t)r * DIM + d] * invd[r];
        runlen++;
    }
    atomicAdd(&sums[cur * DIM + d], acc);
    if (d == 0) atomicAdd(&cnts[cur], (float)runlen);
}

// ---------------- MLP readout ----------------
__global__ void mlp_kernel(const float* __restrict__ sums, const float* __restrict__ cnts,
                           const float* __restrict__ W0, const float* __restrict__ b0,
                           const float* __restrict__ W1, const float* __restrict__ b1,
                           const float* __restrict__ W2, const float* __restrict__ b2,
                           float* __restrict__ out) {
    __shared__ float hg[DIM];
    __shared__ float y0[64];
    __shared__ float y1[32];
    int g = blockIdx.x;
    int t = threadIdx.x;
    float c = cnts[g]; if (c < 1.0f) c = 1.0f;
    hg[t] = sums[g * DIM + t] / c;
    __syncthreads();
    if (t < 64) {
        float acc = b0[t];
        for (int k = 0; k < 128; ++k) acc += hg[k] * W0[k * 64 + t];
        y0[t] = fmaxf(acc, 0.0f);
    }
    __syncthreads();
    if (t < 32) {
        float acc = b1[t];
        for (int k = 0; k < 64; ++k) acc += y0[k] * W1[k * 32 + t];
        y1[t] = fmaxf(acc, 0.0f);
    }
    __syncthreads();
    {
        float acc = b2[t];
        for (int k = 0; k < 32; ++k) acc += y1[k] * W2[k * 128 + t];
        out[g * DIM + t] = acc;
    }
}

extern "C" void kernel_launch(void* const* d_in, const int* in_sizes, int n_in,
                              void* d_out, int out_size, void* d_ws, size_t ws_size,
                              hipStream_t stream) {
    const int*   h_idx = (const int*)d_in[0];
    const int*   src   = (const int*)d_in[2];
    const int*   dst   = (const int*)d_in[3];
    const int*   n2g   = (const int*)d_in[4];
    const float* atom_emb = (const float*)d_in[5];
    const float* layer_W  = (const float*)d_in[7];
    const float* gamma    = (const float*)d_in[8];
    const float* beta     = (const float*)d_in[9];
    const float* W0 = (const float*)d_in[10];
    const float* b0 = (const float*)d_in[11];
    const float* W1 = (const float*)d_in[12];
    const float* b1 = (const float*)d_in[13];
    const float* W2 = (const float*)d_in[14];
    const float* b2 = (const float*)d_in[15];

    const size_t ND = (size_t)N_NODES * DIM;

    // workspace layout (~58 MB)
    _Float16* H16s = (_Float16*)d_ws;                  // ND f16 (dsq-scaled residual X0)
    _Float16* A16s = H16s + ND;                        // ND f16 (dsq-scaled X1)
    _Float16* B16s = A16s + ND;                        // ND f16 (dsq-scaled X2)
    _Float16* Out16 = B16s + ND;                       // ND f16 (gemm out)
    int2*     ebuf  = (int2*)Out16;                    // E int2 — aliases Out16 (dead until gemm)
    _Float16* Wpack = Out16 + ND;                      // 4*49152 f16
    float* dsq  = (float*)(Wpack + NLAYER * WSZ);      // N
    float* invd = dsq + N_NODES;                       // N
    int*   row_ptr = (int*)(invd + N_NODES);           // N+1
    int*   csr_src = row_ptr + N_NODES + 1;            // E
    int*   bcnt = csr_src + N_EDGES;                   // NBUCK
    int*   boff = bcnt + NBUCK;                        // NBUCK+1
    int*   bcur = boff + NBUCK + 1;                    // NBUCK
    float* stats4 = (float*)(bcur + NBUCK);            // 4 * 2*DIM
    float* psums = stats4 + NLAYER * 2 * DIM;          // BGRAPH*DIM
    float* pcnts = psums + BGRAPH * DIM;               // BGRAPH

    hipMemsetAsync(stats4, 0,
                   (NLAYER * 2 * DIM + BGRAPH * DIM + BGRAPH) * sizeof(float), stream);

    // ---- CSR build v2 ----
    hipMemsetAsync(bcnt, 0, NBUCK * sizeof(int), stream);
    bcount_kernel<<<128, 1024, 0, stream>>>(dst, bcnt);
    bscan_kernel<<<1, 256, 0, stream>>>(bcnt, boff, bcur);
    bexpand_kernel<<<(N_EDGES + EB_PER - 1) / EB_PER, 1024, 0, stream>>>(src, dst, bcur, ebuf);
    bbuild_kernel<<<NBUCK, 256, 0, stream>>>(ebuf, boff, row_ptr, dsq, invd, csr_src);
    wcvt_kernel<<<(NLAYER * WSZ + 255) / 256, 256, 0, stream>>>(layer_W, Wpack);

    encode_kernel<<<N_NODES, DIM, 0, stream>>>(h_idx, atom_emb, dsq, H16s);

    const int gemmGrid = (N_NODES + 127) / 128;
    for (int l = 0; l < NLAYER; ++l) {
        prop_kernel<<<4 * PROP_BLOCKS, 256, 0, stream>>>(row_ptr, csr_src, dsq, invd,
                                                         H16s, H16s, -1.0f, 0.0f, A16s);
        prop_kernel<<<4 * PROP_BLOCKS, 256, 0, stream>>>(row_ptr, csr_src, dsq, invd,
                                                         A16s, H16s, -2.0f, -1.0f, B16s);

        float* stats = stats4 + l * 2 * DIM;
        gemm_kernel<<<gemmGrid, 256, 0, stream>>>(H16s, A16s, B16s, invd,
                                                  Wpack + (size_t)l * WSZ, Out16, stats);

        bnapply_kernel<<<((int)ND + 255) / 256, 256, 0, stream>>>(Out16, stats,
                                                  gamma + l * DIM, beta + l * DIM, dsq, invd, H16s);
    }

    pool_kernel<<<(N_NODES + PCHUNK - 1) / PCHUNK, DIM, 0, stream>>>(H16s, invd, n2g, psums, pcnts);
    mlp_kernel<<<BGRAPH, DIM, 0, stream>>>(psums, pcnts, W0, b0, W1, b1, W2, b2, (float*)d_out);
}

// Round 14
// 542.000 us; speedup vs baseline: 1.2629x; 1.2629x over previous
//
#include <hip/hip_runtime.h>

#define N_NODES 50000
#define N_EDGES 800000
#define BGRAPH  256
#define DIM     128
#define NLAYER  4
#define EPS     1e-5f
#define NBUCK   ((N_NODES + 255) / 256)   // 196 buckets of 256 nodes
#define WSZ     (384 * DIM)               // 49152 weights per layer
#define EB_PER  4096                      // edges per bexpand block
#define PROP_BLOCKS ((N_NODES + 31) / 32) // 1563 blocks per column-pass

typedef _Float16 half8_t __attribute__((ext_vector_type(8)));
typedef float    f32x4   __attribute__((ext_vector_type(4)));

// ---------------- CSR build v2: bucketed, write-locality-friendly ----------------
__global__ __launch_bounds__(1024) void bcount_kernel(const int* __restrict__ dst,
                                                      int* __restrict__ bcnt) {
    __shared__ int h[NBUCK];
    int t = threadIdx.x;
    if (t < NBUCK) h[t] = 0;
    __syncthreads();
    for (int e = blockIdx.x * 1024 + t; e < N_EDGES; e += gridDim.x * 1024)
        atomicAdd(&h[dst[e] >> 8], 1);
    __syncthreads();
    if (t < NBUCK && h[t]) atomicAdd(&bcnt[t], h[t]);
}

__global__ void bscan_kernel(const int* __restrict__ bcnt, int* __restrict__ boff,
                             int* __restrict__ bcur) {
    __shared__ int lds[256];
    int t = threadIdx.x;
    int v = (t < NBUCK) ? bcnt[t] : 0;
    lds[t] = v;
    __syncthreads();
    for (int off = 1; off < 256; off <<= 1) {
        int u = (t >= off) ? lds[t - off] : 0;
        __syncthreads();
        lds[t] += u;
        __syncthreads();
    }
    if (t < NBUCK) { int ex = lds[t] - v; boff[t] = ex; bcur[t] = ex; }
    if (t == NBUCK - 1) boff[NBUCK] = lds[t];
}

__global__ __launch_bounds__(1024) void bexpand_kernel(const int* __restrict__ src,
                                                       const int* __restrict__ dst,
                                                       int* __restrict__ bcur,
                                                       int2* __restrict__ ebuf) {
    __shared__ int2 stage[EB_PER];       // 32 KB
    __shared__ int hist[NBUCK];
    __shared__ int lofs[NBUCK];
    __shared__ int lcur[NBUCK];
    __shared__ int gbase[NBUCK];
    __shared__ int s[256];
    int t = threadIdx.x;
    int e0 = blockIdx.x * EB_PER;
    int total = N_EDGES - e0; if (total > EB_PER) total = EB_PER;
    if (t < NBUCK) hist[t] = 0;
    __syncthreads();
    int mys[4], myd[4], myb[4];
#pragma unroll
    for (int j = 0; j < 4; ++j) {
        int e = e0 + t + j * 1024;
        if (e < N_EDGES) {
            mys[j] = src[e]; myd[j] = dst[e]; myb[j] = myd[j] >> 8;
            atomicAdd(&hist[myb[j]], 1);
        } else myb[j] = -1;
    }
    __syncthreads();
    if (t < 256) s[t] = (t < NBUCK) ? hist[t] : 0;
    __syncthreads();
    for (int off = 1; off < 256; off <<= 1) {
        int u = 0;
        if (t < 256 && t >= off) u = s[t - off];
        __syncthreads();
        if (t < 256) s[t] += u;
        __syncthreads();
    }
    if (t < NBUCK) {
        int v = hist[t];
        int ex = s[t] - v;
        lofs[t] = ex; lcur[t] = ex;
        gbase[t] = (v > 0) ? atomicAdd(&bcur[t], v) : 0;
    }
    __syncthreads();
#pragma unroll
    for (int j = 0; j < 4; ++j) if (myb[j] >= 0) {
        int p = atomicAdd(&lcur[myb[j]], 1);
        stage[p] = make_int2(mys[j], myd[j]);
    }
    __syncthreads();
    for (int i = t; i < total; i += 1024) {
        int2 p = stage[i];
        int bu = p.y >> 8;
        ebuf[gbase[bu] + (i - lofs[bu])] = p;
    }
}

__global__ __launch_bounds__(256) void bbuild_kernel(const int2* __restrict__ ebuf,
                                                     const int* __restrict__ boff,
                                                     int* __restrict__ row_ptr,
                                                     float* __restrict__ dsq,
                                                     float* __restrict__ invd,
                                                     int* __restrict__ csr_src) {
    __shared__ int hist[256];
    __shared__ int s[256];
    __shared__ int lcur[256];
    int b = blockIdx.x, t = threadIdx.x;
    int base = boff[b], cnt = boff[b + 1] - base;
    int node0 = b << 8;
    hist[t] = 0;
    __syncthreads();
    for (int i = t; i < cnt; i += 256)
        atomicAdd(&hist[ebuf[base + i].y & 255], 1);
    __syncthreads();
    int v = hist[t];
    s[t] = v;
    __syncthreads();
    for (int off = 1; off < 256; off <<= 1) {
        int u = (t >= off) ? s[t - off] : 0;
        __syncthreads();
        s[t] += u;
        __syncthreads();
    }
    int excl = s[t] - v;
    lcur[t] = excl;
    int n = node0 + t;
    if (n < N_NODES) {
        row_ptr[n] = base + excl;
        float d = (float)(v < 1 ? 1 : v);
        dsq[n] = 1.0f / sqrtf(d);
        invd[n] = sqrtf(d);
        if (n == N_NODES - 1) row_ptr[N_NODES] = base + excl + v;   // = E
    }
    __syncthreads();
    for (int i = t; i < cnt; i += 256) {
        int2 p = ebuf[base + i];
        int slot = atomicAdd(&lcur[p.y & 255], 1);
        csr_src[base + slot] = p.x;
    }
}

// ---------------- W pack to MFMA B-fragment order ----------------
__global__ void wcvt_kernel(const float* __restrict__ W, _Float16* __restrict__ Wp) {
    int idx = blockIdx.x * blockDim.x + threadIdx.x;
    if (idx >= NLAYER * WSZ) return;
    int l = idx / WSZ;
    int r = idx - l * WSZ;
    int j = r & 7, lane = (r >> 3) & 63, t = (r >> 9) & 7, kb = r >> 12;
    int k = (kb << 5) + ((lane >> 4) << 3) + j;
    int n = (t << 4) + (lane & 15);
    Wp[idx] = (_Float16)W[l * WSZ + (k << 7) + n];
}

// ---------------- atom encoder: H16s = f16(dsq*H) only ----------------
__global__ void encode_kernel(const int* __restrict__ h_idx,
                              const float* __restrict__ atom_emb,
                              const float* __restrict__ dsq,
                              _Float16* __restrict__ H16s) {
    int n = blockIdx.x;
    int d = threadIdx.x;
    float acc = 0.0f;
#pragma unroll
    for (int f = 0; f < 9; ++f) {
        int idx = h_idx[n * 9 + f];
        acc += atom_emb[(f * 100 + idx) * DIM + d];
    }
    H16s[n * DIM + d] = (_Float16)(acc * dsq[n]);
}

// ---------------- pull prop (R12 measured-best): 2 column passes, 8 lanes/node ----------------
#define ACC8(r) { _Pragma("unroll") for (int jj = 0; jj < 8; ++jj) acc[jj] += (float)(r)[jj]; }
__global__ void prop_kernel(const int* __restrict__ row_ptr, const int* __restrict__ csr_src,
                            const float* __restrict__ dsq, const float* __restrict__ invd,
                            const _Float16* __restrict__ Gin, const _Float16* __restrict__ X0s,
                            float alpha, float beta, _Float16* __restrict__ Gout) {
    int pass = (blockIdx.x >= PROP_BLOCKS) ? 1 : 0;
    int blk  = blockIdx.x - pass * PROP_BLOCKS;
    int n = blk * 32 + (threadIdx.x >> 3);
    if (n >= N_NODES) return;
    int q = (pass << 6) + ((threadIdx.x & 7) << 3);    // f16 column offset
    const _Float16* gq = Gin + q;
    int i = row_ptr[n], endp = row_ptr[n + 1];
    float acc[8];
#pragma unroll
    for (int j = 0; j < 8; ++j) acc[j] = 0.f;

    if (i + 8 <= endp) {
        int s0 = csr_src[i], s1 = csr_src[i+1], s2 = csr_src[i+2], s3 = csr_src[i+3];
        half8_t a0 = *(const half8_t*)&gq[(size_t)s0 * DIM];
        half8_t a1 = *(const half8_t*)&gq[(size_t)s1 * DIM];
        half8_t a2 = *(const half8_t*)&gq[(size_t)s2 * DIM];
        half8_t a3 = *(const half8_t*)&gq[(size_t)s3 * DIM];
        i += 4;
        for (; i + 4 <= endp; i += 4) {
            int t0 = csr_src[i], t1 = csr_src[i+1], t2 = csr_src[i+2], t3 = csr_src[i+3];
            half8_t b0 = *(const half8_t*)&gq[(size_t)t0 * DIM];
            half8_t b1 = *(const half8_t*)&gq[(size_t)t1 * DIM];
            half8_t b2 = *(const half8_t*)&gq[(size_t)t2 * DIM];
            half8_t b3 = *(const half8_t*)&gq[(size_t)t3 * DIM];
            ACC8(a0); ACC8(a1); ACC8(a2); ACC8(a3);
            a0 = b0; a1 = b1; a2 = b2; a3 = b3;
        }
        ACC8(a0); ACC8(a1); ACC8(a2); ACC8(a3);
    } else if (i + 4 <= endp) {
        int s0 = csr_src[i], s1 = csr_src[i+1], s2 = csr_src[i+2], s3 = csr_src[i+3];
        half8_t r0 = *(const half8_t*)&gq[(size_t)s0 * DIM];
        half8_t r1 = *(const half8_t*)&gq[(size_t)s1 * DIM];
        half8_t r2 = *(const half8_t*)&gq[(size_t)s2 * DIM];
        half8_t r3 = *(const half8_t*)&gq[(size_t)s3 * DIM];
        ACC8(r0); ACC8(r1); ACC8(r2); ACC8(r3);
        i += 4;
    }
    for (; i < endp; ++i) {
        int s = csr_src[i];
        half8_t r = *(const half8_t*)&gq[(size_t)s * DIM];
        ACC8(r);
    }

    float g = dsq[n];
    float a = alpha * g;
    half8_t out;
    if (beta != 0.0f) {
        float bi = beta * invd[n];
        half8_t x0 = *(const half8_t*)&X0s[(size_t)n * DIM + q];
#pragma unroll
        for (int j = 0; j < 8; ++j)
            out[j] = (_Float16)((a * acc[j] + bi * (float)x0[j]) * g);
    } else {
#pragma unroll
        for (int j = 0; j < 8; ++j)
            out[j] = (_Float16)(a * acc[j] * g);
    }
    *(half8_t*)&Gout[(size_t)n * DIM + q] = out;
}

// ---------------- MFMA GEMM v4: software-pipelined A+W loads ----------------
__global__ __launch_bounds__(256) void gemm_kernel(
        const _Float16* __restrict__ X0s, const _Float16* __restrict__ X1s,
        const _Float16* __restrict__ X2s, const float* __restrict__ invd,
        const _Float16* __restrict__ Wp,
        _Float16* __restrict__ Out16, float* __restrict__ stats) {
    const int tid  = threadIdx.x;
    const int wave = tid >> 6;
    const int lane = tid & 63;
    const int quad = lane >> 4;
    const int l15  = lane & 15;
    const int row0 = blockIdx.x * 128 + wave * 32;
    const int rA = row0 + l15;
    const int rB = row0 + 16 + l15;
    const int rAc = (rA < N_NODES) ? rA : (N_NODES - 1);
    const int rBc = (rB < N_NODES) ? rB : (N_NODES - 1);
    const _Float16 h0 = (_Float16)((rA < N_NODES) ? invd[rA] : 0.0f);
    const _Float16 h1 = (_Float16)((rB < N_NODES) ? invd[rB] : 0.0f);

    f32x4 acc0[8], acc1[8];
#pragma unroll
    for (int t = 0; t < 8; ++t) {
        acc0[t] = (f32x4){0.f, 0.f, 0.f, 0.f};
        acc1[t] = (f32x4){0.f, 0.f, 0.f, 0.f};
    }

    const _Float16* bufs[3] = {X0s, X1s, X2s};

    half8_t a0c, a1c, a0n, a1n, bc[8], bn[8];
    {
        const _Float16* Xb = bufs[0];
        const int c0 = (quad << 3);
        a0c = *(const half8_t*)&Xb[(size_t)rAc * DIM + c0];
        a1c = *(const half8_t*)&Xb[(size_t)rBc * DIM + c0];
        const _Float16* wl = Wp + (size_t)lane * 8;
#pragma unroll
        for (int t = 0; t < 8; ++t) bc[t] = *(const half8_t*)&wl[t << 9];
    }

    for (int kb = 0; kb < 12; ++kb) {
        if (kb < 11) {
            const int kn = kb + 1;
            const _Float16* Xb = bufs[kn >> 2];
            const int c0 = ((kn & 3) << 5) + (quad << 3);
            a0n = *(const half8_t*)&Xb[(size_t)rAc * DIM + c0];
            a1n = *(const half8_t*)&Xb[(size_t)rBc * DIM + c0];
            const _Float16* wl = Wp + (size_t)((kn << 9) + lane) * 8;
#pragma unroll
            for (int t = 0; t < 8; ++t) bn[t] = *(const half8_t*)&wl[t << 9];
        }
        half8_t a0, a1;
#pragma unroll
        for (int j = 0; j < 8; ++j) { a0[j] = a0c[j] * h0; a1[j] = a1c[j] * h1; }
#pragma unroll
        for (int t = 0; t < 8; ++t) {
            acc0[t] = __builtin_amdgcn_mfma_f32_16x16x32_f16(a0, bc[t], acc0[t], 0, 0, 0);
            acc1[t] = __builtin_amdgcn_mfma_f32_16x16x32_f16(a1, bc[t], acc1[t], 0, 0, 0);
        }
        if (kb < 11) {
            a0c = a0n; a1c = a1n;
#pragma unroll
            for (int t = 0; t < 8; ++t) bc[t] = bn[t];
        }
    }

    __shared__ float sred[4][DIM];
    __shared__ float s2red[4][DIM];
#pragma unroll
    for (int t = 0; t < 8; ++t) {
        const int c = (t << 4) + l15;
        float s = 0.f, s2 = 0.f;
#pragma unroll
        for (int reg = 0; reg < 4; ++reg) {
            float v0 = acc0[t][reg];
            float v1 = acc1[t][reg];
            s += v0 + v1; s2 += v0 * v0 + v1 * v1;
            int r0r = row0 + (quad << 2) + reg;
            int r1r = r0r + 16;
            if (r0r < N_NODES) Out16[(size_t)r0r * DIM + c] = (_Float16)v0;
            if (r1r < N_NODES) Out16[(size_t)r1r * DIM + c] = (_Float16)v1;
        }
        s  += __shfl_xor(s, 16);  s  += __shfl_xor(s, 32);
        s2 += __shfl_xor(s2, 16); s2 += __shfl_xor(s2, 32);
        if (quad == 0) { sred[wave][c] = s; s2red[wave][c] = s2; }
    }
    __syncthreads();
    if (tid < DIM) {
        float s = 0.f, s2 = 0.f;
#pragma unroll
        for (int w = 0; w < 4; ++w) { s += sred[w][tid]; s2 += s2red[w][tid]; }
        atomicAdd(&stats[tid], s);
        atomicAdd(&stats[DIM + tid], s2);
    }
}

// ---------------- BN apply + relu + residual (H16s-only residual stream) ----------------
__global__ void bnapply_kernel(const _Float16* __restrict__ Out16, const float* __restrict__ stats,
                               const float* __restrict__ gamma, const float* __restrict__ beta,
                               const float* __restrict__ dsq, const float* __restrict__ invd,
                               _Float16* __restrict__ H16s) {
    int idx = blockIdx.x * blockDim.x + threadIdx.x;
    if (idx >= N_NODES * DIM) return;
    int d = idx & 127;
    int n = idx >> 7;
    const float invN = 1.0f / (float)N_NODES;
    float mu  = stats[d] * invN;
    float var = stats[DIM + d] * invN - mu * mu;
    float sc  = (1.0f / sqrtf(var + EPS)) * gamma[d];
    float sh  = beta[d] - mu * sc;
    float v = (float)Out16[idx] * sc + sh;
    float h = (float)H16s[idx] * invd[n] + fmaxf(v, 0.0f);
    H16s[idx] = (_Float16)(h * dsq[n]);
}

// ---------------- mean pool (reconstruct H = H16s*invd) ----------------
#define PCHUNK 64
__global__ void pool_kernel(const _Float16* __restrict__ H16s, const float* __restrict__ invd,
                            const int* __restrict__ n2g,
                            float* __restrict__ sums, float* __restrict__ cnts) {
    int d = threadIdx.x;
    int r0 = blockIdx.x * PCHUNK;
    int rend = r0 + PCHUNK; if (rend > N_NODES) rend = N_NODES;
    if (r0 >= N_NODES) return;
    float acc = 0.0f;
    int cur = n2g[r0];
    int runlen = 0;
    for (int r = r0; r < rend; ++r) {
        int g = n2g[r];
        if (g != cur) {
            atomicAdd(&sums[cur * DIM + d], acc);
            if (d == 0) atomicAdd(&cnts[cur], (float)runlen);
            acc = 0.0f; runlen = 0; cur = g;
        }
        acc += (float)H16s[(size_t)r * DIM + d] * invd[r];
        runlen++;
    }
    atomicAdd(&sums[cur * DIM + d], acc);
    if (d == 0) atomicAdd(&cnts[cur], (float)runlen);
}

// ---------------- MLP readout ----------------
__global__ void mlp_kernel(const float* __restrict__ sums, const float* __restrict__ cnts,
                           const float* __restrict__ W0, const float* __restrict__ b0,
                           const float* __restrict__ W1, const float* __restrict__ b1,
                           const float* __restrict__ W2, const float* __restrict__ b2,
                           float* __restrict__ out) {
    __shared__ float hg[DIM];
    __shared__ float y0[64];
    __shared__ float y1[32];
    int g = blockIdx.x;
    int t = threadIdx.x;
    float c = cnts[g]; if (c < 1.0f) c = 1.0f;
    hg[t] = sums[g * DIM + t] / c;
    __syncthreads();
    if (t < 64) {
        float acc = b0[t];
        for (int k = 0; k < 128; ++k) acc += hg[k] * W0[k * 64 + t];
        y0[t] = fmaxf(acc, 0.0f);
    }
    __syncthreads();
    if (t < 32) {
        float acc = b1[t];
        for (int k = 0; k < 64; ++k) acc += y0[k] * W1[k * 32 + t];
        y1[t] = fmaxf(acc, 0.0f);
    }
    __syncthreads();
    {
        float acc = b2[t];
        for (int k = 0; k < 32; ++k) acc += y1[k] * W2[k * 128 + t];
        out[g * DIM + t] = acc;
    }
}

extern "C" void kernel_launch(void* const* d_in, const int* in_sizes, int n_in,
                              void* d_out, int out_size, void* d_ws, size_t ws_size,
                              hipStream_t stream) {
    const int*   h_idx = (const int*)d_in[0];
    const int*   src   = (const int*)d_in[2];
    const int*   dst   = (const int*)d_in[3];
    const int*   n2g   = (const int*)d_in[4];
    const float* atom_emb = (const float*)d_in[5];
    const float* layer_W  = (const float*)d_in[7];
    const float* gamma    = (const float*)d_in[8];
    const float* beta     = (const float*)d_in[9];
    const float* W0 = (const float*)d_in[10];
    const float* b0 = (const float*)d_in[11];
    const float* W1 = (const float*)d_in[12];
    const float* b1 = (const float*)d_in[13];
    const float* W2 = (const float*)d_in[14];
    const float* b2 = (const float*)d_in[15];

    const size_t ND = (size_t)N_NODES * DIM;

    // workspace layout (~58 MB)
    _Float16* H16s = (_Float16*)d_ws;                  // ND f16 (dsq-scaled residual X0)
    _Float16* A16s = H16s + ND;                        // ND f16 (dsq-scaled X1)
    _Float16* B16s = A16s + ND;                        // ND f16 (dsq-scaled X2)
    _Float16* Out16 = B16s + ND;                       // ND f16 (gemm out)
    int2*     ebuf  = (int2*)Out16;                    // E int2 — aliases Out16 (dead until gemm)
    _Float16* Wpack = Out16 + ND;                      // 4*49152 f16
    float* dsq  = (float*)(Wpack + NLAYER * WSZ);      // N
    float* invd = dsq + N_NODES;                       // N
    int*   row_ptr = (int*)(invd + N_NODES);           // N+1
    int*   csr_src = row_ptr + N_NODES + 1;            // E
    int*   boff = csr_src + N_EDGES;                   // NBUCK+1
    int*   bcur = boff + NBUCK + 1;                    // NBUCK
    // contiguous zero-region: stats4 | psums | pcnts | bcnt  (one memset)
    float* stats4 = (float*)(bcur + NBUCK);            // 4 * 2*DIM
    float* psums = stats4 + NLAYER * 2 * DIM;          // BGRAPH*DIM
    float* pcnts = psums + BGRAPH * DIM;               // BGRAPH
    int*   bcnt  = (int*)(pcnts + BGRAPH);             // NBUCK

    hipMemsetAsync(stats4, 0,
                   (NLAYER * 2 * DIM + BGRAPH * DIM + BGRAPH + NBUCK) * sizeof(float), stream);

    // ---- CSR build v2 ----
    bcount_kernel<<<128, 1024, 0, stream>>>(dst, bcnt);
    bscan_kernel<<<1, 256, 0, stream>>>(bcnt, boff, bcur);
    bexpand_kernel<<<(N_EDGES + EB_PER - 1) / EB_PER, 1024, 0, stream>>>(src, dst, bcur, ebuf);
    bbuild_kernel<<<NBUCK, 256, 0, stream>>>(ebuf, boff, row_ptr, dsq, invd, csr_src);
    wcvt_kernel<<<(NLAYER * WSZ + 255) / 256, 256, 0, stream>>>(layer_W, Wpack);

    encode_kernel<<<N_NODES, DIM, 0, stream>>>(h_idx, atom_emb, dsq, H16s);

    const int gemmGrid = (N_NODES + 127) / 128;
    for (int l = 0; l < NLAYER; ++l) {
        prop_kernel<<<2 * PROP_BLOCKS, 256, 0, stream>>>(row_ptr, csr_src, dsq, invd,
                                                         H16s, H16s, -1.0f, 0.0f, A16s);
        prop_kernel<<<2 * PROP_BLOCKS, 256, 0, stream>>>(row_ptr, csr_src, dsq, invd,
                                                         A16s, H16s, -2.0f, -1.0f, B16s);

        float* stats = stats4 + l * 2 * DIM;
        gemm_kernel<<<gemmGrid, 256, 0, stream>>>(H16s, A16s, B16s, invd,
                                                  Wpack + (size_t)l * WSZ, Out16, stats);

        bnapply_kernel<<<((int)ND + 255) / 256, 256, 0, stream>>>(Out16, stats,
                                                  gamma + l * DIM, beta + l * DIM, dsq, invd, H16s);
    }

    pool_kernel<<<(N_NODES + PCHUNK - 1) / PCHUNK, DIM, 0, stream>>>(H16s, invd, n2g, psums, pcnts);
    mlp_kernel<<<BGRAPH, DIM, 0, stream>>>(psums, pcnts, W0, b0, W1, b1, W2, b2, (float*)d_out);
}